// Round 10
// baseline (614.697 us; speedup 1.0000x reference)
//
#include <hip/hip_runtime.h>

#define NTOT 12288
#define NE   196608
#define MAXDEG 64

typedef __attribute__((ext_vector_type(8))) short bf8_t;   // 8 bf16 (4 VGPRs)
typedef __attribute__((ext_vector_type(4))) float f32x4;   // MFMA C/D frag

// turn-local row r (0..2047) of turn t -> global node id
__device__ __forceinline__ int turn_row_map(int r, int t) {
  return (r >> 7) * 768 + t * 128 + (r & 127);
}

// split fp32 into bf16 hi (truncate) + bf16 lo (truncated residual): ~2^-16 rel
__device__ __forceinline__ void splitbf(float x, unsigned short& hi, unsigned short& lo) {
  unsigned u = __float_as_uint(x);
  hi = (unsigned short)(u >> 16);
  float fh = __uint_as_float(u & 0xFFFF0000u);
  lo = (unsigned short)(__float_as_uint(x - fh) >> 16);
}
__device__ __forceinline__ uint2 pack4(unsigned short a, unsigned short b,
                                       unsigned short c, unsigned short d) {
  return make_uint2((unsigned)a | ((unsigned)b << 16), (unsigned)c | ((unsigned)d << 16));
}

// ---- LDS-free 16x64 GEMM unit: one wave, 4 col-tile accs, K=256, split-bf16 ----
// A planes: row-major k-contig, lane nl -> row nl (caller offsets by row0*256)
// B planes: wth/wtl n-major k-contig (caller offsets by nbase*256)
__device__ __forceinline__ void gemm_g(const unsigned short* __restrict__ ah,
                                       const unsigned short* __restrict__ al,
                                       const unsigned short* __restrict__ bh,
                                       const unsigned short* __restrict__ bl,
                                       int nl, int quad, f32x4 acc[4]) {
#pragma unroll
  for (int k0 = 0; k0 < 256; k0 += 32) {
    bf8_t a_h = *(const bf8_t*)(ah + (size_t)nl * 256 + k0 + quad * 8);
    bf8_t a_l = *(const bf8_t*)(al + (size_t)nl * 256 + k0 + quad * 8);
#pragma unroll
    for (int ct = 0; ct < 4; ct++) {
      bf8_t b_h = *(const bf8_t*)(bh + (size_t)(ct * 16 + nl) * 256 + k0 + quad * 8);
      bf8_t b_l = *(const bf8_t*)(bl + (size_t)(ct * 16 + nl) * 256 + k0 + quad * 8);
      acc[ct] = __builtin_amdgcn_mfma_f32_16x16x32_bf16(a_h, b_h, acc[ct], 0, 0, 0);
      acc[ct] = __builtin_amdgcn_mfma_f32_16x16x32_bf16(a_h, b_l, acc[ct], 0, 0, 0);
      acc[ct] = __builtin_amdgcn_mfma_f32_16x16x32_bf16(a_l, b_h, acc[ct], 0, 0, 0);
    }
  }
}
// same but A from LDS planes [16][264]
__device__ __forceinline__ void gemm_l(const unsigned short (*Ah)[264],
                                       const unsigned short (*Al)[264],
                                       const unsigned short* __restrict__ bh,
                                       const unsigned short* __restrict__ bl,
                                       int nl, int quad, f32x4 acc[4]) {
#pragma unroll
  for (int k0 = 0; k0 < 256; k0 += 32) {
    bf8_t a_h = *(const bf8_t*)&Ah[nl][k0 + quad * 8];
    bf8_t a_l = *(const bf8_t*)&Al[nl][k0 + quad * 8];
#pragma unroll
    for (int ct = 0; ct < 4; ct++) {
      bf8_t b_h = *(const bf8_t*)(bh + (size_t)(ct * 16 + nl) * 256 + k0 + quad * 8);
      bf8_t b_l = *(const bf8_t*)(bl + (size_t)(ct * 16 + nl) * 256 + k0 + quad * 8);
      acc[ct] = __builtin_amdgcn_mfma_f32_16x16x32_bf16(a_h, b_h, acc[ct], 0, 0, 0);
      acc[ct] = __builtin_amdgcn_mfma_f32_16x16x32_bf16(a_h, b_l, acc[ct], 0, 0, 0);
      acc[ct] = __builtin_amdgcn_mfma_f32_16x16x32_bf16(a_l, b_h, acc[ct], 0, 0, 0);
    }
  }
}

// ---------------- fused prologue: feat | wconv | adj (after cnt memset) ----------------
__global__ void __launch_bounds__(256)
k_prep(const float* __restrict__ emb, const float* __restrict__ nmask,
       const int* __restrict__ nodeidx,
       const float* __restrict__ W, const float* __restrict__ Wz,
       const float* __restrict__ Wr, const float* __restrict__ Wn,
       const float* __restrict__ Uz, const float* __restrict__ Ur,
       const float* __restrict__ Un,
       const int* __restrict__ esrc, const int* __restrict__ edst, int* __restrict__ cnt,
       float* __restrict__ h, unsigned short* __restrict__ hbh,
       unsigned short* __restrict__ hbl,
       unsigned short* __restrict__ wth, unsigned short* __restrict__ wtl,
       unsigned short* __restrict__ adj) {
  int l = blockIdx.x, tid = threadIdx.x;
  if (l < 3072) {            // feat: NTOT*64 float4 + bf planes
    int i = l * 256 + tid;
    int row = i >> 6;
    int src = nodeidx[row];
    float m = nmask[src];
    float4 v = ((const float4*)emb)[(size_t)src * 64 + (i & 63)];
    v.x *= m; v.y *= m; v.z *= m; v.w *= m;
    ((float4*)h)[i] = v;
    unsigned short h0,l0,h1,l1,h2,l2,h3,l3;
    splitbf(v.x,h0,l0); splitbf(v.y,h1,l1); splitbf(v.z,h2,l2); splitbf(v.w,h3,l3);
    int o = row * 256 + (i & 63) * 4;
    *(uint2*)(hbh + o) = pack4(h0,h1,h2,h3);
    *(uint2*)(hbl + o) = pack4(l0,l1,l2,l3);
  } else if (l < 4864) {     // wconv: weights -> transposed hi/lo planes
    // n-rows: [0,256)=W | [256,512)=Wz | [512,768)=Wr | [768,1024)=Wn
    //         [1024,1280)=Uz | [1280,1536)=Ur | [1536,1792)=Un
    int idx = (l - 3072) * 256 + tid;
    int n = idx >> 8, k = idx & 255;
    float v;
    if (n < 256) v = W[k * 256 + n];
    else if (n < 1024) { int g=(n-256)>>8, c=(n-256)&255; v = (g==0?Wz:g==1?Wr:Wn)[k*256+c]; }
    else if (n < 1536) { int g=(n-1024)>>8, c=(n-1024)&255; v = (g==0?Uz:Ur)[k*256+c]; }
    else v = Un[k * 256 + (n - 1536)];
    unsigned short hh, ll; splitbf(v, hh, ll);
    wth[idx] = hh; wtl[idx] = ll;
  } else {                   // adj
    int e = (l - 4864) * 256 + tid;
    int d = edst[e];
    int pos = atomicAdd(&cnt[d], 1);
    if (pos < MAXDEG) adj[(size_t)d * MAXDEG + pos] = (unsigned short)esrc[e];
  }
}

// ---- k_big: Q=0: blocks [0,768) Wh=h@W + es/ed (all nodes); [768,1536) uacc batch 0
//             Q=1: 768 blocks uacc batch 1
template <int Q>
__global__ void __launch_bounds__(256)
k_big(const unsigned short* __restrict__ hbh, const unsigned short* __restrict__ hbl,
      const unsigned short* __restrict__ wth, const unsigned short* __restrict__ wtl,
      float* __restrict__ Wh, float* __restrict__ uacc,
      const float* __restrict__ bz, const float* __restrict__ br,
      const float* __restrict__ asrc, const float* __restrict__ adst,
      float* __restrict__ es, float* __restrict__ ed) {
  int l = blockIdx.x;
  int tid = threadIdx.x, lane = tid & 63, wv = tid >> 6;
  int quad = lane >> 4, nl = lane & 15;
  int cbase = wv * 64;
  f32x4 acc[4] = {{0.f,0.f,0.f,0.f},{0.f,0.f,0.f,0.f},{0.f,0.f,0.f,0.f},{0.f,0.f,0.f,0.f}};
  if (Q == 0 && l < 768) {
    int row0 = l * 16;
    gemm_g(hbh + (size_t)row0 * 256, hbl + (size_t)row0 * 256,
           wth + (size_t)cbase * 256, wtl + (size_t)cbase * 256, nl, quad, acc);
    float pes[4], ped[4];
#pragma unroll
    for (int r = 0; r < 4; r++) { pes[r] = 0.f; ped[r] = 0.f; }
#pragma unroll
    for (int ct = 0; ct < 4; ct++) {
      int col = cbase + ct * 16 + nl;
      float as = asrc[col], ad = adst[col];
#pragma unroll
      for (int r = 0; r < 4; r++) {
        int v = row0 + quad * 4 + r;
        Wh[(size_t)v * 256 + col] = acc[ct][r];
        pes[r] += acc[ct][r] * as;
        ped[r] += acc[ct][r] * ad;
      }
    }
#pragma unroll
    for (int m = 1; m < 16; m <<= 1)
#pragma unroll
      for (int r = 0; r < 4; r++) {
        pes[r] += __shfl_xor(pes[r], m);
        ped[r] += __shfl_xor(ped[r], m);
      }
    if (nl == 0)
#pragma unroll
      for (int r = 0; r < 4; r++) {
        int v = row0 + quad * 4 + r;
        es[v * 4 + wv] = pes[r];
        ed[v * 4 + wv] = ped[r];
      }
  } else {
    int u = (Q == 0) ? (l - 768) : l;
    int cg = u / 384, rowt = u % 384;
    int ub = rowt * 16;
    int node0 = (ub / 384) * 768 + (Q * 3 + ((ub % 384) >> 7)) * 128 + (ub & 127);
    gemm_g(hbh + (size_t)node0 * 256, hbl + (size_t)node0 * 256,
           wth + (size_t)(1024 + cg * 256 + cbase) * 256,
           wtl + (size_t)(1024 + cg * 256 + cbase) * 256, nl, quad, acc);
    const float* bias = (cg == 0) ? bz : br;
#pragma unroll
    for (int ct = 0; ct < 4; ct++) {
      int col = cbase + ct * 16 + nl;
      float bb = bias[col];
#pragma unroll
      for (int r = 0; r < 4; r++) {
        int ur = ub + quad * 4 + r;
        uacc[(size_t)ur * 512 + cg * 256 + col] = acc[ct][r] + bb;
      }
    }
  }
}

// ---- k_turn: fused gates + GRU + next-turn Wh/es/ed. 128 blocks x 16 rows ----
__global__ void __launch_bounds__(256)
k_turn(const unsigned short* __restrict__ mbh, const unsigned short* __restrict__ mbl,
       const unsigned short* __restrict__ wth, const unsigned short* __restrict__ wtl,
       float* __restrict__ h, unsigned short* __restrict__ hbh,
       unsigned short* __restrict__ hbl,
       const float* __restrict__ uacc, const float* __restrict__ bn,
       const float* __restrict__ asrc, const float* __restrict__ adst,
       float* __restrict__ es, float* __restrict__ ed, float* __restrict__ Wh, int t) {
  __shared__ __align__(16) unsigned short P0[16][264], P1[16][264];
  int l = blockIdx.x;
  int tid = threadIdx.x, lane = tid & 63, wv = tid >> 6;
  int quad = lane >> 4, nl = lane & 15;
  int r0 = l * 16;
  int cbase = wv * 64;
  int tm3 = t % 3;
  f32x4 az[4] = {{0,0,0,0},{0,0,0,0},{0,0,0,0},{0,0,0,0}};
  f32x4 ar_[4] = {{0,0,0,0},{0,0,0,0},{0,0,0,0},{0,0,0,0}};
  f32x4 an[4] = {{0,0,0,0},{0,0,0,0},{0,0,0,0},{0,0,0,0}};
  const unsigned short* ah = mbh + (size_t)r0 * 256;
  const unsigned short* al = mbl + (size_t)r0 * 256;
  gemm_g(ah, al, wth + (size_t)(256 + cbase) * 256, wtl + (size_t)(256 + cbase) * 256, nl, quad, az);
  gemm_g(ah, al, wth + (size_t)(512 + cbase) * 256, wtl + (size_t)(512 + cbase) * 256, nl, quad, ar_);
  gemm_g(ah, al, wth + (size_t)(768 + cbase) * 256, wtl + (size_t)(768 + cbase) * 256, nl, quad, an);
  float zreg[4][4], hc[4][4];
#pragma unroll
  for (int ct = 0; ct < 4; ct++) {
    int col = cbase + ct * 16 + nl;
#pragma unroll
    for (int r = 0; r < 4; r++) {
      int rowl = quad * 4 + r;
      int rl = r0 + rowl;
      int v = turn_row_map(rl, t);
      int urow = (rl >> 7) * 384 + tm3 * 128 + (rl & 127);
      float zpre = az[ct][r] + uacc[(size_t)urow * 512 + col];
      float rpre = ar_[ct][r] + uacc[(size_t)urow * 512 + 256 + col];
      zreg[ct][r] = 1.f / (1.f + __expf(-zpre));
      float hv = h[(size_t)v * 256 + col];
      hc[ct][r] = hv;
      float rhv = (1.f / (1.f + __expf(-rpre))) * hv;
      unsigned short hh, ll; splitbf(rhv, hh, ll);
      P0[rowl][col] = hh; P1[rowl][col] = ll;
    }
  }
  __syncthreads();
  f32x4 au[4] = {{0,0,0,0},{0,0,0,0},{0,0,0,0},{0,0,0,0}};
  gemm_l(P0, P1, wth + (size_t)(1536 + cbase) * 256, wtl + (size_t)(1536 + cbase) * 256,
         nl, quad, au);
  __syncthreads();  // all P0/P1 reads complete before overwrite
#pragma unroll
  for (int ct = 0; ct < 4; ct++) {
    int col = cbase + ct * 16 + nl;
    float bnv = bn[col];
#pragma unroll
    for (int r = 0; r < 4; r++) {
      int rowl = quad * 4 + r;
      int v = turn_row_map(r0 + rowl, t);
      float n = tanhf(an[ct][r] + bnv + au[ct][r]);
      float z = zreg[ct][r];
      float hn = (1.f - z) * hc[ct][r] + z * n;
      h[(size_t)v * 256 + col] = hn;
      unsigned short hh, ll; splitbf(hn, hh, ll);
      hbh[(size_t)v * 256 + col] = hh;
      hbl[(size_t)v * 256 + col] = ll;
      P0[rowl][col] = hh; P1[rowl][col] = ll;
    }
  }
  __syncthreads();
  f32x4 aw[4] = {{0,0,0,0},{0,0,0,0},{0,0,0,0},{0,0,0,0}};
  gemm_l(P0, P1, wth + (size_t)cbase * 256, wtl + (size_t)cbase * 256, nl, quad, aw);
  float pes[4], ped[4];
#pragma unroll
  for (int r = 0; r < 4; r++) { pes[r] = 0.f; ped[r] = 0.f; }
#pragma unroll
  for (int ct = 0; ct < 4; ct++) {
    int col = cbase + ct * 16 + nl;
    float as = asrc[col], ad = adst[col];
#pragma unroll
    for (int r = 0; r < 4; r++) {
      int v = turn_row_map(r0 + quad * 4 + r, t);
      Wh[(size_t)v * 256 + col] = aw[ct][r];
      pes[r] += aw[ct][r] * as;
      ped[r] += aw[ct][r] * ad;
    }
  }
#pragma unroll
  for (int m = 1; m < 16; m <<= 1)
#pragma unroll
    for (int r = 0; r < 4; r++) {
      pes[r] += __shfl_xor(pes[r], m);
      ped[r] += __shfl_xor(ped[r], m);
    }
  if (nl == 0)
#pragma unroll
    for (int r = 0; r < 4; r++) {
      int v = turn_row_map(r0 + quad * 4 + r, t);
      es[v * 4 + wv] = pes[r];
      ed[v * 4 + wv] = ped[r];
    }
}

// per-dst attention softmax + message (msg -> bf16 hi/lo planes at turn-local rows)
__global__ void k_attn(const int* __restrict__ cnt, const unsigned short* __restrict__ adj,
                       const float* __restrict__ es, const float* __restrict__ ed,
                       const float* __restrict__ Wh,
                       unsigned short* __restrict__ mbh, unsigned short* __restrict__ mbl,
                       float* __restrict__ score, int t, int allnodes) {
  int gph = blockIdx.x & 15, j = blockIdx.x >> 4;
  int w = (allnodes ? gph * 768 : gph * 128) + j * 4 + (threadIdx.x >> 6);
  int lane = threadIdx.x & 63;
  int head = lane >> 4;
  int v, mrow, storemsg;
  if (allnodes) {
    v = w;
    int bt = v >> 7;
    int tt = bt % 6;
    storemsg = (tt == t);
    mrow = (bt / 6) * 128 + (v & 127);
  } else {
    v = turn_row_map(w, t);
    mrow = w;
    storemsg = 1;
  }
  int deg = cnt[v];
  if (deg > MAXDEG) deg = MAXDEG;
  const unsigned short* row = adj + (size_t)v * MAXDEG;
  float edv = ed[v * 4 + head];
  float m = -1e30f;
  for (int jj = 0; jj < deg; jj++) {
    int s = row[jj];
    float lg = es[s * 4 + head] + edv;
    lg = lg >= 0.f ? lg : 0.2f * lg;
    m = fmaxf(m, lg);
  }
  float den = 0.f;
  float4 acc = make_float4(0.f, 0.f, 0.f, 0.f);
  for (int jj = 0; jj < deg; jj++) {
    int s = row[jj];
    float lg = es[s * 4 + head] + edv;
    lg = lg >= 0.f ? lg : 0.2f * lg;
    float wg = __expf(lg - m);
    den += wg;
    if (storemsg) {
      float4 x = ((const float4*)Wh)[(size_t)s * 64 + lane];
      acc.x += wg * x.x; acc.y += wg * x.y; acc.z += wg * x.z; acc.w += wg * x.w;
    }
  }
  float inv = 1.f / (den + 1e-9f);
  if (storemsg) {
    unsigned short h0,l0,h1,l1,h2,l2,h3,l3;
    splitbf(acc.x * inv, h0, l0); splitbf(acc.y * inv, h1, l1);
    splitbf(acc.z * inv, h2, l2); splitbf(acc.w * inv, h3, l3);
    int o = mrow * 256 + lane * 4;
    *(uint2*)(mbh + o) = pack4(h0, h1, h2, h3);
    *(uint2*)(mbl + o) = pack4(l0, l1, l2, l3);
  }
  if (allnodes) {
    float val = den * inv;
    val += __shfl_xor(val, 16);
    val += __shfl_xor(val, 32);
    if (lane == 0) score[v] = 0.25f * val;
  }
}

__global__ void k_pool(const float* __restrict__ score, const float* __restrict__ h,
                       float* __restrict__ pooled) {
  __shared__ float a[128];
  __shared__ float sinv;
  int bt = blockIdx.x;
  int base = bt * 128;
  int tid = threadIdx.x;
  if (tid < 128) a[tid] = score[base + tid];
  __syncthreads();
  if (tid == 0) {
    float mx = a[0];
    for (int n = 1; n < 128; n++) mx = fmaxf(mx, a[n]);
    float s = 0.f;
    for (int n = 0; n < 128; n++) { float e = __expf(a[n] - mx); a[n] = e; s += e; }
    sinv = 1.f / (s * 128.f);
  }
  __syncthreads();
  float acc = 0.f;
  for (int n = 0; n < 128; n++) acc += a[n] * h[(size_t)(base + n) * 256 + tid];
  pooled[bt * 256 + tid] = acc * sinv;
}

__global__ void k_out(const float* __restrict__ pooled, float* __restrict__ out) {
  int i = blockIdx.x * blockDim.x + threadIdx.x;
  if (i >= 8192) return;
  int spk = i >> 12, b = (i >> 8) & 15, c = i & 255;
  float s = 0.f;
  for (int t = spk; t < 6; t += 2) s += pooled[(b * 6 + t) * 256 + c];
  out[i] = s;
}

extern "C" void kernel_launch(void* const* d_in, const int* in_sizes, int n_in,
                              void* d_out, int out_size, void* d_ws, size_t ws_size,
                              hipStream_t stream) {
  const float* emb    = (const float*)d_in[0];
  const float* nmask  = (const float*)d_in[1];
  const float* W      = (const float*)d_in[2];
  const float* a_src  = (const float*)d_in[3];
  const float* a_dst  = (const float*)d_in[4];
  const float* Wz     = (const float*)d_in[5];
  const float* Uz     = (const float*)d_in[6];
  const float* Wr     = (const float*)d_in[7];
  const float* Ur     = (const float*)d_in[8];
  const float* Wn     = (const float*)d_in[9];
  const float* Un     = (const float*)d_in[10];
  const float* bz     = (const float*)d_in[11];
  const float* br     = (const float*)d_in[12];
  const float* bn     = (const float*)d_in[13];
  const int* nodeidx  = (const int*)d_in[14];
  const int* esrc     = (const int*)d_in[15];
  const int* edst     = (const int*)d_in[16];
  float* out = (float*)d_out;

  char* ws = (char*)d_ws;
  size_t off = 0;
  auto carve = [&](size_t bytes) { char* p = ws + off; off += (bytes + 255) & ~(size_t)255; return p; };
  float* h      = (float*)carve(NTOT * 256 * 4);
  float* Wh     = (float*)carve(NTOT * 256 * 4);
  unsigned short* hbh = (unsigned short*)carve(NTOT * 256 * 2);
  unsigned short* hbl = (unsigned short*)carve(NTOT * 256 * 2);
  unsigned short* mbh = (unsigned short*)carve(2048 * 256 * 2);
  unsigned short* mbl = (unsigned short*)carve(2048 * 256 * 2);
  float* es     = (float*)carve(NTOT * 4 * 4);
  float* ed     = (float*)carve(NTOT * 4 * 4);
  float* uacc   = (float*)carve(6144 * 512 * 4);
  float* score  = (float*)carve(NTOT * 4);
  float* pooled = (float*)carve(96 * 256 * 4);
  int*   cnt    = (int*)carve(NTOT * 4);
  unsigned short* adj = (unsigned short*)carve((size_t)NTOT * MAXDEG * 2);
  unsigned short* wth = (unsigned short*)carve(1792 * 256 * 2);
  unsigned short* wtl = (unsigned short*)carve(1792 * 256 * 2);
  if (off > ws_size) return;  // fail cleanly if workspace too small

  hipMemsetAsync(cnt, 0, NTOT * 4, stream);
  k_prep<<<5632, 256, 0, stream>>>(emb, nmask, nodeidx, W, Wz, Wr, Wn, Uz, Ur, Un,
                                   esrc, edst, cnt, h, hbh, hbl, wth, wtl, adj);
  // Wh/es/ed all nodes (blocks 0..767) + uacc batch0 (768..1535)
  k_big<0><<<1536, 256, 0, stream>>>(hbh, hbl, wth, wtl, Wh, uacc, bz, br,
                                     a_src, a_dst, es, ed);

  for (int t = 0; t < 6; t++) {
    if (t < 5)
      k_attn<<<512, 256, 0, stream>>>(cnt, adj, es, ed, Wh, mbh, mbl, score, t, 0);
    else
      k_attn<<<3072, 256, 0, stream>>>(cnt, adj, es, ed, Wh, mbh, mbl, score, t, 1);
    // fused gates + GRU + next-turn Wh/es/ed for this turn's rows
    k_turn<<<128, 256, 0, stream>>>(mbh, mbl, wth, wtl, h, hbh, hbl, uacc, bn,
                                    a_src, a_dst, es, ed, Wh, t);
    if (t == 2) {
      // uacc batch 1: turns 3-5 (their h rows still untouched)
      k_big<1><<<768, 256, 0, stream>>>(hbh, hbl, wth, wtl, Wh, uacc, bz, br,
                                        a_src, a_dst, es, ed);
    }
  }

  k_pool<<<96, 256, 0, stream>>>(score, h, pooled);
  k_out<<<32, 256, 0, stream>>>(pooled, out);
}

// Round 11
// 450.581 us; speedup vs baseline: 1.3642x; 1.3642x over previous
//
#include <hip/hip_runtime.h>

#define NTOT 12288
#define NE   196608
#define MAXDEG 64

typedef __attribute__((ext_vector_type(8))) short bf8_t;   // 8 bf16 (4 VGPRs)
typedef __attribute__((ext_vector_type(4))) float f32x4;   // MFMA C/D frag

// turn-local row r (0..2047) of turn t -> global node id
__device__ __forceinline__ int turn_row_map(int r, int t) {
  return (r >> 7) * 768 + t * 128 + (r & 127);
}

// split fp32 into bf16 hi (truncate) + bf16 lo (truncated residual): ~2^-16 rel
__device__ __forceinline__ void splitbf(float x, unsigned short& hi, unsigned short& lo) {
  unsigned u = __float_as_uint(x);
  hi = (unsigned short)(u >> 16);
  float fh = __uint_as_float(u & 0xFFFF0000u);
  lo = (unsigned short)(__float_as_uint(x - fh) >> 16);
}
__device__ __forceinline__ uint2 pack4(unsigned short a, unsigned short b,
                                       unsigned short c, unsigned short d) {
  return make_uint2((unsigned)a | ((unsigned)b << 16), (unsigned)c | ((unsigned)d << 16));
}

// ---------------- fused prologue: feat | wconv | adj (after cnt memset) ----------------
__global__ void __launch_bounds__(256)
k_prep(const float* __restrict__ emb, const float* __restrict__ nmask,
       const int* __restrict__ nodeidx,
       const float* __restrict__ W, const float* __restrict__ Wz,
       const float* __restrict__ Wr, const float* __restrict__ Wn,
       const float* __restrict__ Uz, const float* __restrict__ Ur,
       const float* __restrict__ Un,
       const int* __restrict__ esrc, const int* __restrict__ edst, int* __restrict__ cnt,
       float* __restrict__ h, unsigned short* __restrict__ hbh,
       unsigned short* __restrict__ hbl,
       unsigned short* __restrict__ wth, unsigned short* __restrict__ wtl,
       unsigned short* __restrict__ adj) {
  int l = blockIdx.x, tid = threadIdx.x;
  if (l < 3072) {            // feat: NTOT*64 float4 + bf planes
    int i = l * 256 + tid;
    int row = i >> 6;
    int src = nodeidx[row];
    float m = nmask[src];
    float4 v = ((const float4*)emb)[(size_t)src * 64 + (i & 63)];
    v.x *= m; v.y *= m; v.z *= m; v.w *= m;
    ((float4*)h)[i] = v;
    unsigned short h0,l0,h1,l1,h2,l2,h3,l3;
    splitbf(v.x,h0,l0); splitbf(v.y,h1,l1); splitbf(v.z,h2,l2); splitbf(v.w,h3,l3);
    int o = row * 256 + (i & 63) * 4;
    *(uint2*)(hbh + o) = pack4(h0,h1,h2,h3);
    *(uint2*)(hbl + o) = pack4(l0,l1,l2,l3);
  } else if (l < 4864) {     // wconv: weights -> transposed hi/lo planes
    // n-rows: [0,256)=W | [256,512)=Wz | [512,768)=Wr | [768,1024)=Wn
    //         [1024,1280)=Uz | [1280,1536)=Ur | [1536,1792)=Un
    int idx = (l - 3072) * 256 + tid;
    int n = idx >> 8, k = idx & 255;
    float v;
    if (n < 256) v = W[k * 256 + n];
    else if (n < 1024) { int g=(n-256)>>8, c=(n-256)&255; v = (g==0?Wz:g==1?Wr:Wn)[k*256+c]; }
    else if (n < 1536) { int g=(n-1024)>>8, c=(n-1024)&255; v = (g==0?Uz:Ur)[k*256+c]; }
    else v = Un[k * 256 + (n - 1536)];
    unsigned short hh, ll; splitbf(v, hh, ll);
    wth[idx] = hh; wtl[idx] = ll;
  } else {                   // adj
    int e = (l - 4864) * 256 + tid;
    int d = edst[e];
    int pos = atomicAdd(&cnt[d], 1);
    if (pos < MAXDEG) adj[(size_t)d * MAXDEG + pos] = (unsigned short)esrc[e];
  }
}

// -------- split-bf16 MFMA GEMM: 32x64 tile, 256 thr (4 waves), LDS-staged, K=256 --------
// wave wv: rh=wv>>1 (16-row half), ch=wv&1 (32-col half = 2 16-col tiles)
// A from producer-written bf16 hi/lo planes (row-major k-contig) — staging is pure copy.
// MODE 5: blocks [0,1536) Wh=h@W + es/ed all nodes; [1536,3072) uacc batch q=0
// MODE 1: whup rows of turn t (A=h planes via map), Wh + es/ed     grid 256
// MODE 2: gates (A=msg planes), epilogue z/rh/npre                 grid 768
// MODE 3: gru (A=rh planes, B=Un), epilogue -> h fp32 + planes     grid 256
// MODE 4: uacc batch q=1                                           grid 1536
template <int MODE>
__global__ void __launch_bounds__(256)
k_mf(const unsigned short* __restrict__ aph, const unsigned short* __restrict__ apl,
     const unsigned short* __restrict__ wth, const unsigned short* __restrict__ wtl,
     float* __restrict__ Wh, float* __restrict__ hbuf,
     unsigned short* __restrict__ hbh, unsigned short* __restrict__ hbl,
     float* __restrict__ g1, float* __restrict__ uacc,
     unsigned short* __restrict__ rbh, unsigned short* __restrict__ rbl,
     const float* __restrict__ bz, const float* __restrict__ br,
     const float* __restrict__ bn,
     const float* __restrict__ asrc, const float* __restrict__ adst,
     float* __restrict__ es, float* __restrict__ ed, int t) {
  __shared__ __align__(16) unsigned short Ah[32][40], Al[32][40];
  __shared__ __align__(16) unsigned short Bh[64][40], Bl[64][40];
  __shared__ float esb[32][2], edb[32][2];
  int l = blockIdx.x;
  bool m0 = true;
  int bx, by;
  if constexpr (MODE == 5) {
    if (l < 1536) { bx = (l & 31) >> 3; by = (l >> 5) * 8 + (l & 7); }           // 4 x 384
    else { m0 = false; int l2 = l - 1536; bx = (l2 & 63) >> 3; by = (l2 >> 6) * 8 + (l2 & 7); }  // 8 x 192
  } else if constexpr (MODE == 2) { bx = (l % 96) >> 3; by = (l / 96) * 8 + (l & 7); }  // 12 x 64
  else if constexpr (MODE == 4)   { bx = (l & 63) >> 3; by = (l >> 6) * 8 + (l & 7); }  // 8 x 192
  else                            { bx = (l & 31) >> 3; by = (l >> 5) * 8 + (l & 7); }  // 4 x 64

  int tid = threadIdx.x;
  int ar = tid >> 3, aq = tid & 7;    // A staging: 32 rows x 8 uint2
  int bn_ = tid >> 2, bq = tid & 3;   // B staging: 64 n-rows x 4 uint4
  int gmA = by * 32 + ar;
  int arow;
  if constexpr (MODE == 1) arow = turn_row_map(gmA, t);
  else if constexpr (MODE == 5)
    arow = m0 ? gmA : (gmA / 384) * 768 + ((gmA % 384) >> 7) * 128 + (gmA & 127);
  else if constexpr (MODE == 4)
    arow = (gmA / 384) * 768 + (3 + ((gmA % 384) >> 7)) * 128 + (gmA & 127);
  else arow = gmA;  // MODE 2 (msg planes), MODE 3 (rh planes)
  const unsigned short* ahp = aph + (size_t)arow * 256;
  const unsigned short* alp = apl + (size_t)arow * 256;

  int nbase;
  if constexpr (MODE == 5)      nbase = m0 ? bx * 64 : 1024 + bx * 64;
  else if constexpr (MODE == 1) nbase = bx * 64;
  else if constexpr (MODE == 2) nbase = 256 + bx * 64;
  else if constexpr (MODE == 3) nbase = 1536 + bx * 64;
  else                          nbase = 1024 + bx * 64;
  const unsigned short* bhp = wth + (size_t)(nbase + bn_) * 256;
  const unsigned short* blp = wtl + (size_t)(nbase + bn_) * 256;

  int lane = tid & 63, wv = tid >> 6;
  int rh = wv >> 1, ch = wv & 1;
  int quad = lane >> 4, nl = lane & 15;
  f32x4 acc0 = {0.f, 0.f, 0.f, 0.f}, acc1 = {0.f, 0.f, 0.f, 0.f};

  for (int k0 = 0; k0 < 256; k0 += 32) {
    *(uint2*)&Ah[ar][aq * 4] = *(const uint2*)(ahp + k0 + aq * 4);
    *(uint2*)&Al[ar][aq * 4] = *(const uint2*)(alp + k0 + aq * 4);
    *(uint4*)&Bh[bn_][bq * 8] = *(const uint4*)(bhp + k0 + bq * 8);
    *(uint4*)&Bl[bn_][bq * 8] = *(const uint4*)(blp + k0 + bq * 8);
    __syncthreads();
    bf8_t a_h = *(const bf8_t*)&Ah[rh * 16 + nl][quad * 8];
    bf8_t a_l = *(const bf8_t*)&Al[rh * 16 + nl][quad * 8];
    bf8_t bh0 = *(const bf8_t*)&Bh[ch * 32 + nl][quad * 8];
    bf8_t bl0 = *(const bf8_t*)&Bl[ch * 32 + nl][quad * 8];
    bf8_t bh1 = *(const bf8_t*)&Bh[ch * 32 + 16 + nl][quad * 8];
    bf8_t bl1 = *(const bf8_t*)&Bl[ch * 32 + 16 + nl][quad * 8];
    acc0 = __builtin_amdgcn_mfma_f32_16x16x32_bf16(a_h, bh0, acc0, 0, 0, 0);
    acc1 = __builtin_amdgcn_mfma_f32_16x16x32_bf16(a_h, bh1, acc1, 0, 0, 0);
    acc0 = __builtin_amdgcn_mfma_f32_16x16x32_bf16(a_h, bl0, acc0, 0, 0, 0);
    acc1 = __builtin_amdgcn_mfma_f32_16x16x32_bf16(a_h, bl1, acc1, 0, 0, 0);
    acc0 = __builtin_amdgcn_mfma_f32_16x16x32_bf16(a_l, bh0, acc0, 0, 0, 0);
    acc1 = __builtin_amdgcn_mfma_f32_16x16x32_bf16(a_l, bh1, acc1, 0, 0, 0);
    __syncthreads();
  }

  // D layout: row = by*32 + rh*16 + quad*4 + r ; cols c0 = bx-block + ch*32 + nl, c1 = c0+16
  int gr = by * 32 + rh * 16 + quad * 4;
  if constexpr (MODE == 5 || MODE == 1) {
    if (MODE == 5 && !m0) {  // uacc batch 0 epilogue
#pragma unroll
      for (int r = 0; r < 4; r++) {
        int grr = gr + r;  // row index into uacc (0..6143)
#pragma unroll
        for (int ct = 0; ct < 2; ct++) {
          float D = (ct == 0) ? acc0[r] : acc1[r];
          int col = bx * 64 + ch * 32 + ct * 16 + nl;
          float bias = (col < 256) ? bz[col] : br[col - 256];
          uacc[(size_t)grr * 512 + col] = D + bias;
        }
      }
    } else {  // Wh + es/ed epilogue
      int c0 = bx * 64 + ch * 32 + nl, c1 = c0 + 16;
      float a0 = asrc[c0], a1 = asrc[c1], d0 = adst[c0], d1 = adst[c1];
      float pes[4], ped[4];
#pragma unroll
      for (int r = 0; r < 4; r++) {
        int v = (MODE == 5) ? (gr + r) : turn_row_map(gr + r, t);
        float x0 = acc0[r], x1 = acc1[r];
        Wh[(size_t)v * 256 + c0] = x0;
        Wh[(size_t)v * 256 + c1] = x1;
        pes[r] = x0 * a0 + x1 * a1;
        ped[r] = x0 * d0 + x1 * d1;
      }
#pragma unroll
      for (int m = 1; m < 16; m <<= 1)
#pragma unroll
        for (int r = 0; r < 4; r++) {
          pes[r] += __shfl_xor(pes[r], m);
          ped[r] += __shfl_xor(ped[r], m);
        }
      if (nl == 0)
#pragma unroll
        for (int r = 0; r < 4; r++) {
          esb[rh * 16 + quad * 4 + r][ch] = pes[r];
          edb[rh * 16 + quad * 4 + r][ch] = ped[r];
        }
      __syncthreads();
      if (tid < 32) {
        int m = tid;
        int v = (MODE == 5) ? (by * 32 + m) : turn_row_map(by * 32 + m, t);
        es[v * 4 + bx] = esb[m][0] + esb[m][1];
        ed[v * 4 + bx] = edb[m][0] + edb[m][1];
      }
    }
  } else if constexpr (MODE == 2) {
    int g = bx >> 2;
    int tm3 = t % 3;
#pragma unroll
    for (int r = 0; r < 4; r++) {
      int grr = gr + r;
      int v = turn_row_map(grr, t);
      int urow = (grr >> 7) * 384 + tm3 * 128 + (grr & 127);
#pragma unroll
      for (int ct = 0; ct < 2; ct++) {
        float D = (ct == 0) ? acc0[r] : acc1[r];
        int c = (bx & 3) * 64 + ch * 32 + ct * 16 + nl;
        if (g == 0) {
          g1[(size_t)grr * 512 + c] = D + uacc[(size_t)urow * 512 + c];
        } else if (g == 1) {
          float rpre = D + uacc[(size_t)urow * 512 + 256 + c];
          float rv = 1.f / (1.f + __expf(-rpre));
          float rhv = rv * hbuf[(size_t)v * 256 + c];
          unsigned short hh, ll; splitbf(rhv, hh, ll);
          rbh[grr * 256 + c] = hh; rbl[grr * 256 + c] = ll;
        } else {
          g1[(size_t)grr * 512 + 256 + c] = D + bn[c];
        }
      }
    }
  } else if constexpr (MODE == 3) {
#pragma unroll
    for (int r = 0; r < 4; r++) {
      int grr = gr + r;
      int v = turn_row_map(grr, t);
#pragma unroll
      for (int ct = 0; ct < 2; ct++) {
        float D = (ct == 0) ? acc0[r] : acc1[r];
        int c = bx * 64 + ch * 32 + ct * 16 + nl;
        float zpre = g1[(size_t)grr * 512 + c];
        float npre = g1[(size_t)grr * 512 + 256 + c] + D;
        float z = 1.f / (1.f + __expf(-zpre));
        float n = tanhf(npre);
        float hv = hbuf[(size_t)v * 256 + c];
        float hn = (1.f - z) * hv + z * n;
        hbuf[(size_t)v * 256 + c] = hn;
        unsigned short hh, ll; splitbf(hn, hh, ll);
        hbh[(size_t)v * 256 + c] = hh;
        hbl[(size_t)v * 256 + c] = ll;
      }
    }
  } else {  // MODE 4: uacc batch 1
#pragma unroll
    for (int r = 0; r < 4; r++) {
      int grr = gr + r;
#pragma unroll
      for (int ct = 0; ct < 2; ct++) {
        float D = (ct == 0) ? acc0[r] : acc1[r];
        int col = bx * 64 + ch * 32 + ct * 16 + nl;
        float bias = (col < 256) ? bz[col] : br[col - 256];
        uacc[(size_t)grr * 512 + col] = D + bias;
      }
    }
  }
}

// per-dst attention softmax + message (msg -> bf16 hi/lo planes at turn-local rows)
__global__ void k_attn(const int* __restrict__ cnt, const unsigned short* __restrict__ adj,
                       const float* __restrict__ es, const float* __restrict__ ed,
                       const float* __restrict__ Wh,
                       unsigned short* __restrict__ mbh, unsigned short* __restrict__ mbl,
                       float* __restrict__ score, int t, int allnodes) {
  int gph = blockIdx.x & 15, j = blockIdx.x >> 4;
  int w = (allnodes ? gph * 768 : gph * 128) + j * 4 + (threadIdx.x >> 6);
  int lane = threadIdx.x & 63;
  int head = lane >> 4;
  int v, mrow, storemsg;
  if (allnodes) {
    v = w;
    int bt = v >> 7;
    int tt = bt % 6;
    storemsg = (tt == t);
    mrow = (bt / 6) * 128 + (v & 127);
  } else {
    v = turn_row_map(w, t);
    mrow = w;
    storemsg = 1;
  }
  int deg = cnt[v];
  if (deg > MAXDEG) deg = MAXDEG;
  const unsigned short* row = adj + (size_t)v * MAXDEG;
  float edv = ed[v * 4 + head];
  float m = -1e30f;
  for (int jj = 0; jj < deg; jj++) {
    int s = row[jj];
    float lg = es[s * 4 + head] + edv;
    lg = lg >= 0.f ? lg : 0.2f * lg;
    m = fmaxf(m, lg);
  }
  float den = 0.f;
  float4 acc = make_float4(0.f, 0.f, 0.f, 0.f);
  for (int jj = 0; jj < deg; jj++) {
    int s = row[jj];
    float lg = es[s * 4 + head] + edv;
    lg = lg >= 0.f ? lg : 0.2f * lg;
    float wg = __expf(lg - m);
    den += wg;
    if (storemsg) {
      float4 x = ((const float4*)Wh)[(size_t)s * 64 + lane];
      acc.x += wg * x.x; acc.y += wg * x.y; acc.z += wg * x.z; acc.w += wg * x.w;
    }
  }
  float inv = 1.f / (den + 1e-9f);
  if (storemsg) {
    unsigned short h0,l0,h1,l1,h2,l2,h3,l3;
    splitbf(acc.x * inv, h0, l0); splitbf(acc.y * inv, h1, l1);
    splitbf(acc.z * inv, h2, l2); splitbf(acc.w * inv, h3, l3);
    int o = mrow * 256 + lane * 4;
    *(uint2*)(mbh + o) = pack4(h0, h1, h2, h3);
    *(uint2*)(mbl + o) = pack4(l0, l1, l2, l3);
  }
  if (allnodes) {
    float val = den * inv;
    val += __shfl_xor(val, 16);
    val += __shfl_xor(val, 32);
    if (lane == 0) score[v] = 0.25f * val;
  }
}

// one block per (b,t): softmax over 128 node scores, then weighted mean of h
__global__ void k_pool(const float* __restrict__ score, const float* __restrict__ h,
                       float* __restrict__ pooled) {
  __shared__ float a[128];
  __shared__ float sinv;
  int bt = blockIdx.x;
  int base = bt * 128;
  int tid = threadIdx.x;
  if (tid < 128) a[tid] = score[base + tid];
  __syncthreads();
  if (tid == 0) {
    float mx = a[0];
    for (int n = 1; n < 128; n++) mx = fmaxf(mx, a[n]);
    float s = 0.f;
    for (int n = 0; n < 128; n++) { float e = __expf(a[n] - mx); a[n] = e; s += e; }
    sinv = 1.f / (s * 128.f);
  }
  __syncthreads();
  float acc = 0.f;
  for (int n = 0; n < 128; n++) acc += a[n] * h[(size_t)(base + n) * 256 + tid];
  pooled[bt * 256 + tid] = acc * sinv;
}

__global__ void k_out(const float* __restrict__ pooled, float* __restrict__ out) {
  int i = blockIdx.x * blockDim.x + threadIdx.x;
  if (i >= 8192) return;
  int spk = i >> 12, b = (i >> 8) & 15, c = i & 255;
  float s = 0.f;
  for (int t = spk; t < 6; t += 2) s += pooled[(b * 6 + t) * 256 + c];
  out[i] = s;
}

extern "C" void kernel_launch(void* const* d_in, const int* in_sizes, int n_in,
                              void* d_out, int out_size, void* d_ws, size_t ws_size,
                              hipStream_t stream) {
  const float* emb    = (const float*)d_in[0];
  const float* nmask  = (const float*)d_in[1];
  const float* W      = (const float*)d_in[2];
  const float* a_src  = (const float*)d_in[3];
  const float* a_dst  = (const float*)d_in[4];
  const float* Wz     = (const float*)d_in[5];
  const float* Uz     = (const float*)d_in[6];
  const float* Wr     = (const float*)d_in[7];
  const float* Ur     = (const float*)d_in[8];
  const float* Wn     = (const float*)d_in[9];
  const float* Un     = (const float*)d_in[10];
  const float* bz     = (const float*)d_in[11];
  const float* br     = (const float*)d_in[12];
  const float* bn     = (const float*)d_in[13];
  const int* nodeidx  = (const int*)d_in[14];
  const int* esrc     = (const int*)d_in[15];
  const int* edst     = (const int*)d_in[16];
  float* out = (float*)d_out;

  char* ws = (char*)d_ws;
  size_t off = 0;
  auto carve = [&](size_t bytes) { char* p = ws + off; off += (bytes + 255) & ~(size_t)255; return p; };
  float* h      = (float*)carve(NTOT * 256 * 4);
  float* Wh     = (float*)carve(NTOT * 256 * 4);
  unsigned short* hbh = (unsigned short*)carve(NTOT * 256 * 2);
  unsigned short* hbl = (unsigned short*)carve(NTOT * 256 * 2);
  unsigned short* mbh = (unsigned short*)carve(2048 * 256 * 2);
  unsigned short* mbl = (unsigned short*)carve(2048 * 256 * 2);
  unsigned short* rbh = (unsigned short*)carve(2048 * 256 * 2);
  unsigned short* rbl = (unsigned short*)carve(2048 * 256 * 2);
  float* es     = (float*)carve(NTOT * 4 * 4);
  float* ed     = (float*)carve(NTOT * 4 * 4);
  float* g1     = (float*)carve(2048 * 512 * 4);
  float* uacc   = (float*)carve(6144 * 512 * 4);
  float* score  = (float*)carve(NTOT * 4);
  float* pooled = (float*)carve(96 * 256 * 4);
  int*   cnt    = (int*)carve(NTOT * 4);
  unsigned short* adj = (unsigned short*)carve((size_t)NTOT * MAXDEG * 2);
  unsigned short* wth = (unsigned short*)carve(1792 * 256 * 2);
  unsigned short* wtl = (unsigned short*)carve(1792 * 256 * 2);
  if (off > ws_size) return;  // fail cleanly if workspace too small

  hipMemsetAsync(cnt, 0, NTOT * 4, stream);
  k_prep<<<5632, 256, 0, stream>>>(emb, nmask, nodeidx, W, Wz, Wr, Wn, Uz, Ur, Un,
                                   esrc, edst, cnt, h, hbh, hbl, wth, wtl, adj);
  // Wh/es/ed all nodes (blocks 0..1535) + uacc batch0 (1536..3071)
  k_mf<5><<<3072, 256, 0, stream>>>(hbh, hbl, wth, wtl, Wh, h, hbh, hbl, g1, uacc,
                                    rbh, rbl, bz, br, bn, a_src, a_dst, es, ed, 0);

  for (int t = 0; t < 6; t++) {
    if (t > 0) {
      // refresh Wh/es/ed for rows changed by last turn's GRU (turn t-1)
      k_mf<1><<<256, 256, 0, stream>>>(hbh, hbl, wth, wtl, Wh, h, hbh, hbl, g1, uacc,
                                       rbh, rbl, bz, br, bn, a_src, a_dst, es, ed, t - 1);
    }
    if (t < 5)
      k_attn<<<512, 256, 0, stream>>>(cnt, adj, es, ed, Wh, mbh, mbl, score, t, 0);
    else
      k_attn<<<3072, 256, 0, stream>>>(cnt, adj, es, ed, Wh, mbh, mbl, score, t, 1);
    k_mf<2><<<768, 256, 0, stream>>>(mbh, mbl, wth, wtl, Wh, h, hbh, hbl, g1, uacc,
                                     rbh, rbl, bz, br, bn, a_src, a_dst, es, ed, t);
    k_mf<3><<<256, 256, 0, stream>>>(rbh, rbl, wth, wtl, Wh, h, hbh, hbl, g1, uacc,
                                     rbh, rbl, bz, br, bn, a_src, a_dst, es, ed, t);
    if (t == 2) {
      // uacc batch 1: turns 3-5 (their h rows still untouched)
      k_mf<4><<<1536, 256, 0, stream>>>(hbh, hbl, wth, wtl, Wh, h, hbh, hbl, g1, uacc,
                                        rbh, rbl, bz, br, bn, a_src, a_dst, es, ed, 1);
    }
  }

  k_pool<<<96, 256, 0, stream>>>(score, h, pooled);
  k_out<<<32, 256, 0, stream>>>(pooled, out);
}

// Round 12
// 415.999 us; speedup vs baseline: 1.4776x; 1.0831x over previous
//
#include <hip/hip_runtime.h>

#define NTOT 12288
#define NE   196608
#define MAXDEG 64

typedef __attribute__((ext_vector_type(8))) short bf8_t;   // 8 bf16 (4 VGPRs)
typedef __attribute__((ext_vector_type(4))) float f32x4;   // MFMA C/D frag

// turn-local row r (0..2047) of turn t -> global node id
__device__ __forceinline__ int turn_row_map(int r, int t) {
  return (r >> 7) * 768 + t * 128 + (r & 127);
}

// split fp32 into bf16 hi (truncate) + bf16 lo (truncated residual): ~2^-16 rel
__device__ __forceinline__ void splitbf(float x, unsigned short& hi, unsigned short& lo) {
  unsigned u = __float_as_uint(x);
  hi = (unsigned short)(u >> 16);
  float fh = __uint_as_float(u & 0xFFFF0000u);
  lo = (unsigned short)(__float_as_uint(x - fh) >> 16);
}
__device__ __forceinline__ float reconf(unsigned short hi, unsigned short lo) {
  return __uint_as_float((unsigned)hi << 16) + __uint_as_float((unsigned)lo << 16);
}
__device__ __forceinline__ uint2 pack4(unsigned short a, unsigned short b,
                                       unsigned short c, unsigned short d) {
  return make_uint2((unsigned)a | ((unsigned)b << 16), (unsigned)c | ((unsigned)d << 16));
}

// ---------------- fused prologue: feat | wconv | adj (after cnt memset) ----------------
__global__ void __launch_bounds__(256)
k_prep(const float* __restrict__ emb, const float* __restrict__ nmask,
       const int* __restrict__ nodeidx,
       const float* __restrict__ W, const float* __restrict__ Wz,
       const float* __restrict__ Wr, const float* __restrict__ Wn,
       const float* __restrict__ Uz, const float* __restrict__ Ur,
       const float* __restrict__ Un,
       const int* __restrict__ esrc, const int* __restrict__ edst, int* __restrict__ cnt,
       unsigned short* __restrict__ hbh, unsigned short* __restrict__ hbl,
       unsigned short* __restrict__ wth, unsigned short* __restrict__ wtl,
       unsigned short* __restrict__ adj) {
  int l = blockIdx.x, tid = threadIdx.x;
  if (l < 3072) {            // feat: NTOT*64 float4 -> bf planes only
    int i = l * 256 + tid;
    int row = i >> 6;
    int src = nodeidx[row];
    float m = nmask[src];
    float4 v = ((const float4*)emb)[(size_t)src * 64 + (i & 63)];
    v.x *= m; v.y *= m; v.z *= m; v.w *= m;
    unsigned short h0,l0,h1,l1,h2,l2,h3,l3;
    splitbf(v.x,h0,l0); splitbf(v.y,h1,l1); splitbf(v.z,h2,l2); splitbf(v.w,h3,l3);
    int o = row * 256 + (i & 63) * 4;
    *(uint2*)(hbh + o) = pack4(h0,h1,h2,h3);
    *(uint2*)(hbl + o) = pack4(l0,l1,l2,l3);
  } else if (l < 4864) {     // wconv: weights -> transposed hi/lo planes
    // n-rows: [0,256)=W | [256,512)=Wz | [512,768)=Wr | [768,1024)=Wn
    //         [1024,1280)=Uz | [1280,1536)=Ur | [1536,1792)=Un
    int idx = (l - 3072) * 256 + tid;
    int n = idx >> 8, k = idx & 255;
    float v;
    if (n < 256) v = W[k * 256 + n];
    else if (n < 1024) { int g=(n-256)>>8, c=(n-256)&255; v = (g==0?Wz:g==1?Wr:Wn)[k*256+c]; }
    else if (n < 1536) { int g=(n-1024)>>8, c=(n-1024)&255; v = (g==0?Uz:Ur)[k*256+c]; }
    else v = Un[k * 256 + (n - 1536)];
    unsigned short hh, ll; splitbf(v, hh, ll);
    wth[idx] = hh; wtl[idx] = ll;
  } else {                   // adj
    int e = (l - 4864) * 256 + tid;
    int d = edst[e];
    int pos = atomicAdd(&cnt[d], 1);
    if (pos < MAXDEG) adj[(size_t)d * MAXDEG + pos] = (unsigned short)esrc[e];
  }
}

// -------- split-bf16 MFMA GEMM: 32x64 tile, 256 thr (4 waves), LDS-staged, K=256 --------
// MODE 5: blocks [0,1536) Wh=h@W + es/ed all nodes; [1536,3072) uacc batch q=0
// MODE 1: whup rows of turn t (A=h planes via map), Wh + es/ed     grid 256
// MODE 2: gates (A=msg planes), epilogue z/rh/npre                 grid 768
// MODE 3: gru (A=rh planes, B=Un), epilogue -> h planes            grid 256 (264 at t=5:
//         blocks 256..263 zero out[8192] for the fused pool epilogue)
// MODE 4: uacc batch q=1                                           grid 1536
template <int MODE>
__global__ void __launch_bounds__(256)
k_mf(const unsigned short* __restrict__ aph, const unsigned short* __restrict__ apl,
     const unsigned short* __restrict__ wth, const unsigned short* __restrict__ wtl,
     float* __restrict__ Wh,
     unsigned short* __restrict__ hbh, unsigned short* __restrict__ hbl,
     float* __restrict__ g1, float* __restrict__ uacc,
     unsigned short* __restrict__ rbh, unsigned short* __restrict__ rbl,
     const float* __restrict__ bz, const float* __restrict__ br,
     const float* __restrict__ bn,
     const float* __restrict__ asrc, const float* __restrict__ adst,
     float* __restrict__ es, float* __restrict__ ed, float* __restrict__ outp, int t) {
  __shared__ __align__(16) unsigned short Ah[32][40], Al[32][40];
  __shared__ __align__(16) unsigned short Bh[64][40], Bl[64][40];
  __shared__ float esb[32][2], edb[32][2];
  int l = blockIdx.x;
  int tid = threadIdx.x;
  if constexpr (MODE == 3) {
    if (l >= 256) {  // out-zero blocks (only launched at t=5)
      ((float4*)outp)[(l - 256) * 256 + tid] = make_float4(0.f, 0.f, 0.f, 0.f);
      return;
    }
  }
  bool m0 = true;
  int bx, by;
  if constexpr (MODE == 5) {
    if (l < 1536) { bx = (l & 31) >> 3; by = (l >> 5) * 8 + (l & 7); }           // 4 x 384
    else { m0 = false; int l2 = l - 1536; bx = (l2 & 63) >> 3; by = (l2 >> 6) * 8 + (l2 & 7); }  // 8 x 192
  } else if constexpr (MODE == 2) { bx = (l % 96) >> 3; by = (l / 96) * 8 + (l & 7); }  // 12 x 64
  else if constexpr (MODE == 4)   { bx = (l & 63) >> 3; by = (l >> 6) * 8 + (l & 7); }  // 8 x 192
  else                            { bx = (l & 31) >> 3; by = (l >> 5) * 8 + (l & 7); }  // 4 x 64

  int ar = tid >> 3, aq = tid & 7;    // A staging: 32 rows x 8 uint2
  int bn_ = tid >> 2, bq = tid & 3;   // B staging: 64 n-rows x 4 uint4
  int gmA = by * 32 + ar;
  int arow;
  if constexpr (MODE == 1) arow = turn_row_map(gmA, t);
  else if constexpr (MODE == 5)
    arow = m0 ? gmA : (gmA / 384) * 768 + ((gmA % 384) >> 7) * 128 + (gmA & 127);
  else if constexpr (MODE == 4)
    arow = (gmA / 384) * 768 + (3 + ((gmA % 384) >> 7)) * 128 + (gmA & 127);
  else arow = gmA;  // MODE 2 (msg planes), MODE 3 (rh planes)
  const unsigned short* ahp = aph + (size_t)arow * 256;
  const unsigned short* alp = apl + (size_t)arow * 256;

  int nbase;
  if constexpr (MODE == 5)      nbase = m0 ? bx * 64 : 1024 + bx * 64;
  else if constexpr (MODE == 1) nbase = bx * 64;
  else if constexpr (MODE == 2) nbase = 256 + bx * 64;
  else if constexpr (MODE == 3) nbase = 1536 + bx * 64;
  else                          nbase = 1024 + bx * 64;
  const unsigned short* bhp = wth + (size_t)(nbase + bn_) * 256;
  const unsigned short* blp = wtl + (size_t)(nbase + bn_) * 256;

  int lane = tid & 63, wv = tid >> 6;
  int rh = wv >> 1, ch = wv & 1;
  int quad = lane >> 4, nl = lane & 15;
  f32x4 acc0 = {0.f, 0.f, 0.f, 0.f}, acc1 = {0.f, 0.f, 0.f, 0.f};

  for (int k0 = 0; k0 < 256; k0 += 32) {
    *(uint2*)&Ah[ar][aq * 4] = *(const uint2*)(ahp + k0 + aq * 4);
    *(uint2*)&Al[ar][aq * 4] = *(const uint2*)(alp + k0 + aq * 4);
    *(uint4*)&Bh[bn_][bq * 8] = *(const uint4*)(bhp + k0 + bq * 8);
    *(uint4*)&Bl[bn_][bq * 8] = *(const uint4*)(blp + k0 + bq * 8);
    __syncthreads();
    bf8_t a_h = *(const bf8_t*)&Ah[rh * 16 + nl][quad * 8];
    bf8_t a_l = *(const bf8_t*)&Al[rh * 16 + nl][quad * 8];
    bf8_t bh0 = *(const bf8_t*)&Bh[ch * 32 + nl][quad * 8];
    bf8_t bl0 = *(const bf8_t*)&Bl[ch * 32 + nl][quad * 8];
    bf8_t bh1 = *(const bf8_t*)&Bh[ch * 32 + 16 + nl][quad * 8];
    bf8_t bl1 = *(const bf8_t*)&Bl[ch * 32 + 16 + nl][quad * 8];
    acc0 = __builtin_amdgcn_mfma_f32_16x16x32_bf16(a_h, bh0, acc0, 0, 0, 0);
    acc1 = __builtin_amdgcn_mfma_f32_16x16x32_bf16(a_h, bh1, acc1, 0, 0, 0);
    acc0 = __builtin_amdgcn_mfma_f32_16x16x32_bf16(a_h, bl0, acc0, 0, 0, 0);
    acc1 = __builtin_amdgcn_mfma_f32_16x16x32_bf16(a_h, bl1, acc1, 0, 0, 0);
    acc0 = __builtin_amdgcn_mfma_f32_16x16x32_bf16(a_l, bh0, acc0, 0, 0, 0);
    acc1 = __builtin_amdgcn_mfma_f32_16x16x32_bf16(a_l, bh1, acc1, 0, 0, 0);
    __syncthreads();
  }

  // D layout: row = by*32 + rh*16 + quad*4 + r ; cols c0 = bx-block + ch*32 + nl, c1 = c0+16
  int gr = by * 32 + rh * 16 + quad * 4;
  if constexpr (MODE == 5 || MODE == 1) {
    if (MODE == 5 && !m0) {  // uacc batch 0 epilogue
#pragma unroll
      for (int r = 0; r < 4; r++) {
        int grr = gr + r;
#pragma unroll
        for (int ct = 0; ct < 2; ct++) {
          float D = (ct == 0) ? acc0[r] : acc1[r];
          int col = bx * 64 + ch * 32 + ct * 16 + nl;
          float bias = (col < 256) ? bz[col] : br[col - 256];
          uacc[(size_t)grr * 512 + col] = D + bias;
        }
      }
    } else {  // Wh + es/ed epilogue
      int c0 = bx * 64 + ch * 32 + nl, c1 = c0 + 16;
      float a0 = asrc[c0], a1 = asrc[c1], d0 = adst[c0], d1 = adst[c1];
      float pes[4], ped[4];
#pragma unroll
      for (int r = 0; r < 4; r++) {
        int v = (MODE == 5) ? (gr + r) : turn_row_map(gr + r, t);
        float x0 = acc0[r], x1 = acc1[r];
        Wh[(size_t)v * 256 + c0] = x0;
        Wh[(size_t)v * 256 + c1] = x1;
        pes[r] = x0 * a0 + x1 * a1;
        ped[r] = x0 * d0 + x1 * d1;
      }
#pragma unroll
      for (int m = 1; m < 16; m <<= 1)
#pragma unroll
        for (int r = 0; r < 4; r++) {
          pes[r] += __shfl_xor(pes[r], m);
          ped[r] += __shfl_xor(ped[r], m);
        }
      if (nl == 0)
#pragma unroll
        for (int r = 0; r < 4; r++) {
          esb[rh * 16 + quad * 4 + r][ch] = pes[r];
          edb[rh * 16 + quad * 4 + r][ch] = ped[r];
        }
      __syncthreads();
      if (tid < 32) {
        int m = tid;
        int v = (MODE == 5) ? (by * 32 + m) : turn_row_map(by * 32 + m, t);
        es[v * 4 + bx] = esb[m][0] + esb[m][1];
        ed[v * 4 + bx] = edb[m][0] + edb[m][1];
      }
    }
  } else if constexpr (MODE == 2) {
    int g = bx >> 2;
    int tm3 = t % 3;
#pragma unroll
    for (int r = 0; r < 4; r++) {
      int grr = gr + r;
      int v = turn_row_map(grr, t);
      int urow = (grr >> 7) * 384 + tm3 * 128 + (grr & 127);
#pragma unroll
      for (int ct = 0; ct < 2; ct++) {
        float D = (ct == 0) ? acc0[r] : acc1[r];
        int c = (bx & 3) * 64 + ch * 32 + ct * 16 + nl;
        if (g == 0) {
          g1[(size_t)grr * 512 + c] = D + uacc[(size_t)urow * 512 + c];
        } else if (g == 1) {
          float rpre = D + uacc[(size_t)urow * 512 + 256 + c];
          float rv = 1.f / (1.f + __expf(-rpre));
          int hidx = v * 256 + c;
          float hv = reconf(hbh[hidx], hbl[hidx]);
          float rhv = rv * hv;
          unsigned short hh, ll; splitbf(rhv, hh, ll);
          rbh[grr * 256 + c] = hh; rbl[grr * 256 + c] = ll;
        } else {
          g1[(size_t)grr * 512 + 256 + c] = D + bn[c];
        }
      }
    }
  } else if constexpr (MODE == 3) {
#pragma unroll
    for (int r = 0; r < 4; r++) {
      int grr = gr + r;
      int v = turn_row_map(grr, t);
#pragma unroll
      for (int ct = 0; ct < 2; ct++) {
        float D = (ct == 0) ? acc0[r] : acc1[r];
        int c = bx * 64 + ch * 32 + ct * 16 + nl;
        float zpre = g1[(size_t)grr * 512 + c];
        float npre = g1[(size_t)grr * 512 + 256 + c] + D;
        float z = 1.f / (1.f + __expf(-zpre));
        float n = tanhf(npre);
        int hidx = v * 256 + c;
        float hv = reconf(hbh[hidx], hbl[hidx]);
        float hn = (1.f - z) * hv + z * n;
        unsigned short hh, ll; splitbf(hn, hh, ll);
        hbh[hidx] = hh;
        hbl[hidx] = ll;
      }
    }
  } else {  // MODE 4: uacc batch 1
#pragma unroll
    for (int r = 0; r < 4; r++) {
      int grr = gr + r;
#pragma unroll
      for (int ct = 0; ct < 2; ct++) {
        float D = (ct == 0) ? acc0[r] : acc1[r];
        int col = bx * 64 + ch * 32 + ct * 16 + nl;
        float bias = (col < 256) ? bz[col] : br[col - 256];
        uacc[(size_t)grr * 512 + col] = D + bias;
      }
    }
  }
}

// per-dst attention softmax + message, ONE PASS (logits bounded; 1e-9 eps shift ~1e-9 rel)
__global__ void k_attn(const int* __restrict__ cnt, const unsigned short* __restrict__ adj,
                       const float* __restrict__ es, const float* __restrict__ ed,
                       const float* __restrict__ Wh,
                       unsigned short* __restrict__ mbh, unsigned short* __restrict__ mbl,
                       float* __restrict__ score, int t, int allnodes) {
  int gph = blockIdx.x & 15, j = blockIdx.x >> 4;
  int w = (allnodes ? gph * 768 : gph * 128) + j * 4 + (threadIdx.x >> 6);
  int lane = threadIdx.x & 63;
  int head = lane >> 4;
  int v, mrow, storemsg;
  if (allnodes) {
    v = w;
    int bt = v >> 7;
    int tt = bt % 6;
    storemsg = (tt == t);
    mrow = (bt / 6) * 128 + (v & 127);
  } else {
    v = turn_row_map(w, t);
    mrow = w;
    storemsg = 1;
  }
  int deg = cnt[v];
  if (deg > MAXDEG) deg = MAXDEG;
  const unsigned short* row = adj + (size_t)v * MAXDEG;
  float edv = ed[v * 4 + head];
  float den = 0.f;
  float4 acc = make_float4(0.f, 0.f, 0.f, 0.f);
  for (int jj = 0; jj < deg; jj++) {
    int s = row[jj];
    float lg = es[s * 4 + head] + edv;
    lg = lg >= 0.f ? lg : 0.2f * lg;
    float wg = __expf(lg);
    den += wg;
    if (storemsg) {
      float4 x = ((const float4*)Wh)[(size_t)s * 64 + lane];
      acc.x += wg * x.x; acc.y += wg * x.y; acc.z += wg * x.z; acc.w += wg * x.w;
    }
  }
  float inv = 1.f / (den + 1e-9f);
  if (storemsg) {
    unsigned short h0,l0,h1,l1,h2,l2,h3,l3;
    splitbf(acc.x * inv, h0, l0); splitbf(acc.y * inv, h1, l1);
    splitbf(acc.z * inv, h2, l2); splitbf(acc.w * inv, h3, l3);
    int o = mrow * 256 + lane * 4;
    *(uint2*)(mbh + o) = pack4(h0, h1, h2, h3);
    *(uint2*)(mbl + o) = pack4(l0, l1, l2, l3);
  }
  if (allnodes) {
    float val = den * inv;
    val += __shfl_xor(val, 16);
    val += __shfl_xor(val, 32);
    if (lane == 0) score[v] = 0.25f * val;
  }
}

// one block per (b,t): softmax over 128 node scores, weighted mean of h (from planes),
// atomicAdd into out (zeroed by the t=5 gru dispatch's extra blocks)
__global__ void k_pool(const float* __restrict__ score,
                       const unsigned short* __restrict__ hbh,
                       const unsigned short* __restrict__ hbl,
                       float* __restrict__ out) {
  __shared__ float a[128];
  __shared__ float sinv;
  int bt = blockIdx.x;
  int base = bt * 128;
  int tid = threadIdx.x;
  if (tid < 128) a[tid] = score[base + tid];
  __syncthreads();
  if (tid == 0) {
    float mx = a[0];
    for (int n = 1; n < 128; n++) mx = fmaxf(mx, a[n]);
    float s = 0.f;
    for (int n = 0; n < 128; n++) { float e = __expf(a[n] - mx); a[n] = e; s += e; }
    sinv = 1.f / (s * 128.f);
  }
  __syncthreads();
  float acc = 0.f;
  for (int n = 0; n < 128; n++) {
    int idx = (base + n) * 256 + tid;
    acc += a[n] * reconf(hbh[idx], hbl[idx]);
  }
  int b = bt / 6, tt = bt % 6, spk = tt & 1;
  atomicAdd(&out[spk * 4096 + b * 256 + tid], acc * sinv);
}

extern "C" void kernel_launch(void* const* d_in, const int* in_sizes, int n_in,
                              void* d_out, int out_size, void* d_ws, size_t ws_size,
                              hipStream_t stream) {
  const float* emb    = (const float*)d_in[0];
  const float* nmask  = (const float*)d_in[1];
  const float* W      = (const float*)d_in[2];
  const float* a_src  = (const float*)d_in[3];
  const float* a_dst  = (const float*)d_in[4];
  const float* Wz     = (const float*)d_in[5];
  const float* Uz     = (const float*)d_in[6];
  const float* Wr     = (const float*)d_in[7];
  const float* Ur     = (const float*)d_in[8];
  const float* Wn     = (const float*)d_in[9];
  const float* Un     = (const float*)d_in[10];
  const float* bz     = (const float*)d_in[11];
  const float* br     = (const float*)d_in[12];
  const float* bn     = (const float*)d_in[13];
  const int* nodeidx  = (const int*)d_in[14];
  const int* esrc     = (const int*)d_in[15];
  const int* edst     = (const int*)d_in[16];
  float* out = (float*)d_out;

  char* ws = (char*)d_ws;
  size_t off = 0;
  auto carve = [&](size_t bytes) { char* p = ws + off; off += (bytes + 255) & ~(size_t)255; return p; };
  float* Wh     = (float*)carve(NTOT * 256 * 4);
  unsigned short* hbh = (unsigned short*)carve(NTOT * 256 * 2);
  unsigned short* hbl = (unsigned short*)carve(NTOT * 256 * 2);
  unsigned short* mbh = (unsigned short*)carve(2048 * 256 * 2);
  unsigned short* mbl = (unsigned short*)carve(2048 * 256 * 2);
  unsigned short* rbh = (unsigned short*)carve(2048 * 256 * 2);
  unsigned short* rbl = (unsigned short*)carve(2048 * 256 * 2);
  float* es     = (float*)carve(NTOT * 4 * 4);
  float* ed     = (float*)carve(NTOT * 4 * 4);
  float* g1     = (float*)carve(2048 * 512 * 4);
  float* uacc   = (float*)carve(6144 * 512 * 4);
  float* score  = (float*)carve(NTOT * 4);
  int*   cnt    = (int*)carve(NTOT * 4);
  unsigned short* adj = (unsigned short*)carve((size_t)NTOT * MAXDEG * 2);
  unsigned short* wth = (unsigned short*)carve(1792 * 256 * 2);
  unsigned short* wtl = (unsigned short*)carve(1792 * 256 * 2);
  if (off > ws_size) return;  // fail cleanly if workspace too small

  hipMemsetAsync(cnt, 0, NTOT * 4, stream);
  k_prep<<<5632, 256, 0, stream>>>(emb, nmask, nodeidx, W, Wz, Wr, Wn, Uz, Ur, Un,
                                   esrc, edst, cnt, hbh, hbl, wth, wtl, adj);
  // Wh/es/ed all nodes (blocks 0..1535) + uacc batch0 (1536..3071)
  k_mf<5><<<3072, 256, 0, stream>>>(hbh, hbl, wth, wtl, Wh, hbh, hbl, g1, uacc,
                                    rbh, rbl, bz, br, bn, a_src, a_dst, es, ed, out, 0);

  for (int t = 0; t < 6; t++) {
    if (t > 0) {
      // refresh Wh/es/ed for rows changed by last turn's GRU (turn t-1)
      k_mf<1><<<256, 256, 0, stream>>>(hbh, hbl, wth, wtl, Wh, hbh, hbl, g1, uacc,
                                       rbh, rbl, bz, br, bn, a_src, a_dst, es, ed, out, t - 1);
    }
    if (t < 5)
      k_attn<<<512, 256, 0, stream>>>(cnt, adj, es, ed, Wh, mbh, mbl, score, t, 0);
    else
      k_attn<<<3072, 256, 0, stream>>>(cnt, adj, es, ed, Wh, mbh, mbl, score, t, 1);
    k_mf<2><<<768, 256, 0, stream>>>(mbh, mbl, wth, wtl, Wh, hbh, hbl, g1, uacc,
                                     rbh, rbl, bz, br, bn, a_src, a_dst, es, ed, out, t);
    // gru; at t=5 append 8 blocks that zero out[] for the fused pool epilogue
    k_mf<3><<<(t == 5 ? 264 : 256), 256, 0, stream>>>(rbh, rbl, wth, wtl, Wh, hbh, hbl,
                                                      g1, uacc, rbh, rbl, bz, br, bn,
                                                      a_src, a_dst, es, ed, out, t);
    if (t == 2) {
      // uacc batch 1: turns 3-5 (their h rows still untouched)
      k_mf<4><<<1536, 256, 0, stream>>>(hbh, hbl, wth, wtl, Wh, hbh, hbl, g1, uacc,
                                        rbh, rbl, bz, br, bn, a_src, a_dst, es, ed, out, 1);
    }
  }

  k_pool<<<96, 256, 0, stream>>>(score, hbh, hbl, out);
}